// Round 8
// baseline (345.158 us; speedup 1.0000x reference)
//
#include <hip/hip_runtime.h>
#include <hip/hip_bf16.h>

#define B_    8
#define N_    2048
#define FIN_  256
#define FOUT_ 128
#define NROWS (B_*N_)

typedef __attribute__((ext_vector_type(8))) short short8;
typedef __attribute__((ext_vector_type(4))) float f32x4;

__device__ __forceinline__ float bf2f(unsigned short u) {
  return __uint_as_float(((unsigned int)u) << 16);
}
__device__ __forceinline__ unsigned short f2bf(float f) {
  unsigned int u = __float_as_uint(f);
  u += 0x7FFFu + ((u >> 16) & 1u);   // RNE
  return (unsigned short)(u >> 16);
}
__device__ __forceinline__ float ldin(const void* p, size_t idx, int isbf) {
  if (isbf) return bf2f(((const unsigned short*)p)[idx]);
  return ((const float*)p)[idx];
}
// monotone float->uint encoding for atomicMax-based float max (all enc > 0)
__device__ __forceinline__ unsigned encf(float f) {
  unsigned u = __float_as_uint(f);
  return (u & 0x80000000u) ? ~u : (u | 0x80000000u);
}
__device__ __forceinline__ float decf(unsigned k) {
  return (k & 0x80000000u) ? __uint_as_float(k ^ 0x80000000u) : __uint_as_float(~k);
}

// ---------- kernel A: detect input dtype; init Mdst encodings ----------
__global__ void k_detect(const void* x, int* flag, unsigned* MdstE) {
  __shared__ int cnt[256];
  const unsigned short* u = (const unsigned short*)x;
  if (threadIdx.x < 8) MdstE[threadIdx.x] = 0u;   // enc(f) > 0 for all finite f
  int c = 0;
  for (int i = threadIdx.x; i < 8192; i += 256) {
    unsigned short v = u[i];
    int e = (v >> 7) & 0xFF;
    if ((e >= 110 && e <= 145) || (v & 0x7FFF) == 0) c++;
  }
  cnt[threadIdx.x] = c;
  __syncthreads();
  for (int s = 128; s > 0; s >>= 1) {
    if (threadIdx.x < s) cnt[threadIdx.x] += cnt[threadIdx.x + s];
    __syncthreads();
  }
  if (threadIdx.x == 0) *flag = (cnt[0] > 7373) ? 1 : 0;  // 0.9 * 8192
}

// ---------- kernel 0: blocks 0..127: WT[f][k] = bf16(W[k][f]);
//            block 128: wa[k] = W[k,:]@a_src, wa[256+k] = W[k,:]@a_dst (fp32)
__global__ __launch_bounds__(256)
void k_prep(const void* __restrict__ W, const void* __restrict__ a,
            const int* __restrict__ flag,
            unsigned short* __restrict__ WT, float* __restrict__ wa) {
  const int isbf = *flag;
  if (blockIdx.x < 128) {
    int f = blockIdx.x, k = threadIdx.x;
    WT[f * 256 + k] = f2bf(ldin(W, (size_t)k * 128 + f, isbf));
  } else {
    __shared__ float as_s[256];
    int k = threadIdx.x;
    as_s[k] = ldin(a, k, isbf);
    __syncthreads();
    float s = 0.f, d = 0.f;
    for (int f = 0; f < 128; f++) {
      float w = ldin(W, (size_t)k * 128 + f, isbf);
      s += w * as_s[f];
      d += w * as_s[128 + f];
    }
    wa[k] = s;
    wa[256 + k] = d;
  }
}

// ---------- kernel 1: h = x@W single-bf16 MFMA; emit hT (tiled) -------------
// hT layout: (row j, feat f) at hT[(j>>4)*2048 + f*16 + (j&15)].
// Block: 32 rows, 256 threads (4 waves). Wave w: row-slab w>>1, f-half w&1.
__global__ __launch_bounds__(256)
void k_h(const void* __restrict__ x, const unsigned short* __restrict__ WT,
         const int* __restrict__ flag, unsigned short* __restrict__ hT) {
  __shared__ __align__(16) unsigned short xs[32][264];
  const int isbf = *flag;
  const int t    = threadIdx.x;
  const int row0 = blockIdx.x * 32;

  if (isbf) {
    const unsigned short* xu = (const unsigned short*)x;
#pragma unroll
    for (int u = 0; u < 4; u++) {
      int r = u * 8 + (t >> 5), c = t & 31;
      *(short8*)&xs[r][c * 8] = *(const short8*)&xu[(size_t)(row0 + r) * FIN_ + c * 8];
    }
  } else {
    const float* xf = (const float*)x;
#pragma unroll
    for (int u = 0; u < 4; u++) {
      int r = u * 8 + (t >> 5), c = t & 31;
      float4 v0 = *(const float4*)&xf[(size_t)(row0 + r) * FIN_ + c * 8];
      float4 v1 = *(const float4*)&xf[(size_t)(row0 + r) * FIN_ + c * 8 + 4];
      float vv[8] = {v0.x, v0.y, v0.z, v0.w, v1.x, v1.y, v1.z, v1.w};
      short8 sh;
#pragma unroll
      for (int e = 0; e < 8; e++) sh[e] = (short)f2bf(vv[e]);
      *(short8*)&xs[r][c * 8] = sh;
    }
  }
  __syncthreads();

  const int lane = t & 63, w = t >> 6;
  const int m = lane & 15, quad = lane >> 4;
  const int slab = w >> 1, fh = w & 1;

  f32x4 acc[4];
#pragma unroll
  for (int i = 0; i < 4; i++) acc[i] = (f32x4){0.f, 0.f, 0.f, 0.f};

#pragma unroll
  for (int ks = 0; ks < 8; ks++) {
    short8 ah = *(const short8*)&xs[slab * 16 + m][ks * 32 + quad * 8];
#pragma unroll
    for (int ft = 0; ft < 4; ft++) {
      int f = fh * 64 + ft * 16 + m;
      short8 bh = *(const short8*)&WT[(size_t)f * 256 + ks * 32 + quad * 8];
      acc[ft] = __builtin_amdgcn_mfma_f32_16x16x32_bf16(ah, bh, acc[ft], 0, 0, 0);
    }
  }

  // D: row = quad*4 + r, col = f; chunk = row0/16 + slab
  size_t n0 = (size_t)blockIdx.x * 2 + slab;
  unsigned short* hblk = hT + n0 * (FOUT_ * 16);
#pragma unroll
  for (int ft = 0; ft < 4; ft++) {
    int f = fh * 64 + ft * 16 + m;
    unsigned short p0 = f2bf(acc[ft][0]), p1 = f2bf(acc[ft][1]);
    unsigned short p2 = f2bf(acc[ft][2]), p3 = f2bf(acc[ft][3]);
    *(uint2*)&hblk[f * 16 + quad * 4] = make_uint2(
        (unsigned)p0 | ((unsigned)p1 << 16),
        (unsigned)p2 | ((unsigned)p3 << 16));
  }
}

// ---------- kernel 2: fsrc/fdst = x @ wa (fp32, wave-per-row) + Mdst atomic -
__global__ __launch_bounds__(256)
void k_f(const void* __restrict__ x, const float* __restrict__ wa,
         const int* __restrict__ flag,
         float* __restrict__ fsrc, float* __restrict__ fdst, unsigned* __restrict__ MdstE) {
  __shared__ float wa_s[512];
  const int isbf = *flag;
  const int t = threadIdx.x;
  wa_s[t] = wa[t];
  wa_s[256 + t] = wa[256 + t];
  __syncthreads();

  const int lane = t & 63, w = t >> 6;
  const int row = blockIdx.x * 4 + w;
  float s = 0.f, d = 0.f;
#pragma unroll
  for (int i = 0; i < 4; i++) {
    float xv = ldin(x, (size_t)row * FIN_ + lane * 4 + i, isbf);
    s += xv * wa_s[lane * 4 + i];
    d += xv * wa_s[256 + lane * 4 + i];
  }
#pragma unroll
  for (int off = 32; off >= 1; off >>= 1) {
    s += __shfl_xor(s, off, 64);
    d += __shfl_xor(d, off, 64);
  }
  if (lane == 0) {
    fsrc[row] = s;
    fdst[row] = d;
    atomicMax(&MdstE[row >> 11], encf(d));
  }
}

// ---------- kernel 3: gated attention; prefetched B-frags, single-bf16 p ----
// Grid = B*(N/16) = 1024 blocks, 256 threads. Round-7 verified dataflow
// (p -> LDS phi -> ds_read A-frag -> MFMA), plus:
//  * B-fragments for tile t+1 loaded into registers at top of iter t
//    (before the barrier) -> global latency hidden behind logits+barrier.
//  * lo-half dropped; denominator sums bf16(p) so softmax weights stay
//    exactly normalized (self-consistent numerator/denominator).
__global__ __launch_bounds__(256)
void k_attn(const unsigned short* __restrict__ hT, const void* __restrict__ coord,
            const float* __restrict__ fsrc, const float* __restrict__ fdst,
            const unsigned* __restrict__ MdstE, const int* __restrict__ flag,
            void* __restrict__ out) {
  const int isbf = *flag;
  const int tid = threadIdx.x;
  const int b   = blockIdx.x >> 7;
  const int q0  = (blockIdx.x & 127) * 16;

  __shared__ __align__(16) unsigned short phi[2][16][72];
  __shared__ __align__(16) float cjs[2][64][4];   // (cx,cy,cz,fdst)
  __shared__ float lred[16][16];                  // [jseg][qA]

  const int qA   = tid & 15;
  const int jseg = tid >> 4;
  const size_t qglb = (size_t)b * N_ + q0 + qA;
  const float cq0 = ldin(coord, qglb * 3 + 0, isbf);
  const float cq1 = ldin(coord, qglb * 3 + 1, isbf);
  const float cq2 = ldin(coord, qglb * 3 + 2, isbf);
  const float fsq = fsrc[qglb];
  const float Bq  = fmaxf(0.f, fsq + decf(MdstE[b]));
  float lacc = 0.f;

  const int lane = tid & 63, w = tid >> 6;
  const int m = lane & 15, quad = lane >> 4;
  f32x4 acc[2];
  acc[0] = (f32x4){0.f, 0.f, 0.f, 0.f};
  acc[1] = (f32x4){0.f, 0.f, 0.f, 0.f};

  const unsigned short* hTb = hT + (size_t)b * (N_ * FOUT_);

  // prologue: coords tile 0 + B-fragments tile 0
  if (tid < 64) {
    size_t jg = (size_t)b * N_ + tid;
    cjs[0][tid][0] = ldin(coord, jg * 3 + 0, isbf);
    cjs[0][tid][1] = ldin(coord, jg * 3 + 1, isbf);
    cjs[0][tid][2] = ldin(coord, jg * 3 + 2, isbf);
    cjs[0][tid][3] = fdst[jg];
  }
  short8 bcur[4], bnxt[4];
#pragma unroll
  for (int ks = 0; ks < 2; ks++)
#pragma unroll
    for (int f2 = 0; f2 < 2; f2++) {
      int col = (w * 2 + f2) * 16 + m;
      bcur[ks * 2 + f2] = *(const short8*)&hTb[(size_t)(ks * 2 + (quad >> 1)) * (FOUT_ * 16)
                                               + col * 16 + (quad & 1) * 8];
    }
  __syncthreads();

  for (int t64 = 0; t64 < 32; t64++) {
    const int buf = t64 & 1, nbuf = buf ^ 1;

    // prefetch NEXT tile's B-fragments (global; consumed after next barrier)
    if (t64 < 31) {
      const int jcb = (t64 + 1) * 4;
#pragma unroll
      for (int ks = 0; ks < 2; ks++)
#pragma unroll
        for (int f2 = 0; f2 < 2; f2++) {
          int col = (w * 2 + f2) * 16 + m;
          bnxt[ks * 2 + f2] = *(const short8*)&hTb[(size_t)(jcb + ks * 2 + (quad >> 1)) * (FOUT_ * 16)
                                                   + col * 16 + (quad & 1) * 8];
        }
      // stage NEXT tile's coords
      if (tid < 64) {
        size_t jg = (size_t)b * N_ + (t64 + 1) * 64 + tid;
        cjs[nbuf][tid][0] = ldin(coord, jg * 3 + 0, isbf);
        cjs[nbuf][tid][1] = ldin(coord, jg * 3 + 1, isbf);
        cjs[nbuf][tid][2] = ldin(coord, jg * 3 + 2, isbf);
        cjs[nbuf][tid][3] = fdst[jg];
      }
    }

    // ---- logits -> bf16 p ----
#pragma unroll
    for (int jj = 0; jj < 4; jj++) {
      int jl = jseg * 4 + jj;
      float4 cj = *(const float4*)&cjs[buf][jl][0];
      float dx = cq0 - cj.x, dy = cq1 - cj.y, dz = cq2 - cj.z;
      float d2 = dx * dx + dy * dy + dz * dz;
      float loc = __expf(-0.1f * d2);
      float e = fsq + cj.w;
      e = (e > 0.f) ? e : 0.2f * e;
      float p = (loc > 0.01f) ? __expf(e * loc - Bq) : 0.f;
      unsigned short hb = f2bf(p);
      lacc += bf2f(hb);                 // denominator from the SAME bf16 values
      phi[buf][qA][jl] = hb;
    }
    __syncthreads();   // one barrier per tile

    // ---- PV MFMA with prefetched B ----
#pragma unroll
    for (int ks = 0; ks < 2; ks++) {
      short8 ah = *(const short8*)&phi[buf][m][ks * 32 + quad * 8];
#pragma unroll
      for (int f2 = 0; f2 < 2; f2++)
        acc[f2] = __builtin_amdgcn_mfma_f32_16x16x32_bf16(ah, bcur[ks * 2 + f2], acc[f2], 0, 0, 0);
    }
#pragma unroll
    for (int i = 0; i < 4; i++) bcur[i] = bnxt[i];
  }

  // ---- denominator ----
  lred[jseg][qA] = lacc;
  __syncthreads();
  float dinv[4];
#pragma unroll
  for (int r = 0; r < 4; r++) {
    int q = quad * 4 + r;
    float s = 0.f;
#pragma unroll
    for (int k = 0; k < 16; k++) s += lred[k][q];
    dinv[r] = 1.0f / fmaxf(s, 1e-30f);
  }

  // ---- normalize, elu, store ----
#pragma unroll
  for (int f2 = 0; f2 < 2; f2++) {
    int f = (w * 2 + f2) * 16 + m;
#pragma unroll
    for (int r = 0; r < 4; r++) {
      int q = quad * 4 + r;
      float v = acc[f2][r] * dinv[r];
      v = (v > 0.f) ? v : expm1f(v);
      size_t oidx = ((size_t)(b * N_ + q0 + q)) * FOUT_ + f;
      if (isbf) ((unsigned short*)out)[oidx] = f2bf(v);
      else      ((float*)out)[oidx] = v;
    }
  }
}

extern "C" void kernel_launch(void* const* d_in, const int* in_sizes, int n_in,
                              void* d_out, int out_size, void* d_ws, size_t ws_size,
                              hipStream_t stream) {
  const void* x     = d_in[0];
  const void* coord = d_in[1];
  const void* W     = d_in[2];
  const void* a     = d_in[3];

  // ws: [64-float header: flag @0, MdstE @ +8 uints][hT][WT][wa][fsrc][fdst]
  int*            flag  = (int*)d_ws;
  unsigned*       MdstE = (unsigned*)d_ws + 8;
  unsigned short* hT    = (unsigned short*)((float*)d_ws + 64);
  unsigned short* WT    = hT + (size_t)NROWS * FOUT_;
  float*          wa    = (float*)(WT + 128 * 256);
  float*          fsrc  = wa + 512;
  float*          fdst  = fsrc + NROWS;

  k_detect<<<1, 256, 0, stream>>>(x, flag, MdstE);
  k_prep  <<<129, 256, 0, stream>>>(W, a, flag, WT, wa);
  k_h     <<<NROWS / 32, 256, 0, stream>>>(x, WT, flag, hT);
  k_f     <<<NROWS / 4, 256, 0, stream>>>(x, wa, flag, fsrc, fdst, MdstE);
  k_attn  <<<B_ * (N_ / 16), 256, 0, stream>>>(hT, coord, fsrc, fdst, MdstE, flag, d_out);
}

// Round 9
// 162.061 us; speedup vs baseline: 2.1298x; 2.1298x over previous
//
#include <hip/hip_runtime.h>
#include <hip/hip_bf16.h>

#define B_    8
#define N_    2048
#define FIN_  256
#define FOUT_ 128
#define NROWS (B_*N_)

typedef __attribute__((ext_vector_type(8))) short short8;
typedef __attribute__((ext_vector_type(4))) float f32x4;

__device__ __forceinline__ float bf2f(unsigned short u) {
  return __uint_as_float(((unsigned int)u) << 16);
}
__device__ __forceinline__ unsigned short f2bf(float f) {
  unsigned int u = __float_as_uint(f);
  u += 0x7FFFu + ((u >> 16) & 1u);   // RNE
  return (unsigned short)(u >> 16);
}
__device__ __forceinline__ float ldin(const void* p, size_t idx, int isbf) {
  if (isbf) return bf2f(((const unsigned short*)p)[idx]);
  return ((const float*)p)[idx];
}

// ---------- kernel A: detect input dtype from x's bit patterns ----------
__global__ void k_detect(const void* x, int* flag) {
  __shared__ int cnt[256];
  const unsigned short* u = (const unsigned short*)x;
  int c = 0;
  for (int i = threadIdx.x; i < 8192; i += 256) {
    unsigned short v = u[i];
    int e = (v >> 7) & 0xFF;
    if ((e >= 110 && e <= 145) || (v & 0x7FFF) == 0) c++;
  }
  cnt[threadIdx.x] = c;
  __syncthreads();
  for (int s = 128; s > 0; s >>= 1) {
    if (threadIdx.x < s) cnt[threadIdx.x] += cnt[threadIdx.x + s];
    __syncthreads();
  }
  if (threadIdx.x == 0) *flag = (cnt[0] > 7373) ? 1 : 0;  // 0.9 * 8192
}

// ---------- kernel 0: blocks 0..127: WT[f][k] = bf16(W[k][f]);
//            block 128: wa[k] = W[k,:]@a_src, wa[256+k] = W[k,:]@a_dst (fp32)
__global__ __launch_bounds__(256)
void k_prep(const void* __restrict__ W, const void* __restrict__ a,
            const int* __restrict__ flag,
            unsigned short* __restrict__ WT, float* __restrict__ wa) {
  const int isbf = *flag;
  if (blockIdx.x < 128) {
    int f = blockIdx.x, k = threadIdx.x;
    WT[f * 256 + k] = f2bf(ldin(W, (size_t)k * 128 + f, isbf));
  } else {
    __shared__ float as_s[256];
    int k = threadIdx.x;
    as_s[k] = ldin(a, k, isbf);
    __syncthreads();
    float s = 0.f, d = 0.f;
    for (int f = 0; f < 128; f++) {
      float w = ldin(W, (size_t)k * 128 + f, isbf);
      s += w * as_s[f];
      d += w * as_s[128 + f];
    }
    wa[k] = s;
    wa[256 + k] = d;
  }
}

// ---------- kernel 1: h = x@W single-bf16 MFMA; emit hT (tiled) -------------
// hT layout: (row j, feat f) at hT[(j>>4)*2048 + f*16 + (j&15)].
// Block: 32 rows, 256 threads (4 waves). Wave w: row-slab w>>1, f-half w&1.
__global__ __launch_bounds__(256)
void k_h(const void* __restrict__ x, const unsigned short* __restrict__ WT,
         const int* __restrict__ flag, unsigned short* __restrict__ hT) {
  __shared__ __align__(16) unsigned short xs[32][264];
  const int isbf = *flag;
  const int t    = threadIdx.x;
  const int row0 = blockIdx.x * 32;

  if (isbf) {
    const unsigned short* xu = (const unsigned short*)x;
#pragma unroll
    for (int u = 0; u < 4; u++) {
      int r = u * 8 + (t >> 5), c = t & 31;
      *(short8*)&xs[r][c * 8] = *(const short8*)&xu[(size_t)(row0 + r) * FIN_ + c * 8];
    }
  } else {
    const float* xf = (const float*)x;
#pragma unroll
    for (int u = 0; u < 4; u++) {
      int r = u * 8 + (t >> 5), c = t & 31;
      float4 v0 = *(const float4*)&xf[(size_t)(row0 + r) * FIN_ + c * 8];
      float4 v1 = *(const float4*)&xf[(size_t)(row0 + r) * FIN_ + c * 8 + 4];
      float vv[8] = {v0.x, v0.y, v0.z, v0.w, v1.x, v1.y, v1.z, v1.w};
      short8 sh;
#pragma unroll
      for (int e = 0; e < 8; e++) sh[e] = (short)f2bf(vv[e]);
      *(short8*)&xs[r][c * 8] = sh;
    }
  }
  __syncthreads();

  const int lane = t & 63, w = t >> 6;
  const int m = lane & 15, quad = lane >> 4;
  const int slab = w >> 1, fh = w & 1;

  f32x4 acc[4];
#pragma unroll
  for (int i = 0; i < 4; i++) acc[i] = (f32x4){0.f, 0.f, 0.f, 0.f};

#pragma unroll
  for (int ks = 0; ks < 8; ks++) {
    short8 ah = *(const short8*)&xs[slab * 16 + m][ks * 32 + quad * 8];
#pragma unroll
    for (int ft = 0; ft < 4; ft++) {
      int f = fh * 64 + ft * 16 + m;
      short8 bh = *(const short8*)&WT[(size_t)f * 256 + ks * 32 + quad * 8];
      acc[ft] = __builtin_amdgcn_mfma_f32_16x16x32_bf16(ah, bh, acc[ft], 0, 0, 0);
    }
  }

  // D: row = quad*4 + r, col = f; chunk = row0/16 + slab
  size_t n0 = (size_t)blockIdx.x * 2 + slab;
  unsigned short* hblk = hT + n0 * (FOUT_ * 16);
#pragma unroll
  for (int ft = 0; ft < 4; ft++) {
    int f = fh * 64 + ft * 16 + m;
    unsigned short p0 = f2bf(acc[ft][0]), p1 = f2bf(acc[ft][1]);
    unsigned short p2 = f2bf(acc[ft][2]), p3 = f2bf(acc[ft][3]);
    *(uint2*)&hblk[f * 16 + quad * 4] = make_uint2(
        (unsigned)p0 | ((unsigned)p1 << 16),
        (unsigned)p2 | ((unsigned)p3 << 16));
  }
}

// ---------- kernel 2: fsrc/fdst = x @ wa (fp32, wave-per-row) — NO atomics --
__global__ __launch_bounds__(256)
void k_f(const void* __restrict__ x, const float* __restrict__ wa,
         const int* __restrict__ flag,
         float* __restrict__ fsrc, float* __restrict__ fdst) {
  __shared__ float wa_s[512];
  const int isbf = *flag;
  const int t = threadIdx.x;
  wa_s[t] = wa[t];
  wa_s[256 + t] = wa[256 + t];
  __syncthreads();

  const int lane = t & 63, w = t >> 6;
  const int row = blockIdx.x * 4 + w;
  float xv[4];
  if (isbf) {
    const unsigned short* xu = (const unsigned short*)x + (size_t)row * FIN_ + lane * 4;
    uint2 u = *(const uint2*)xu;
    xv[0] = bf2f((unsigned short)(u.x & 0xFFFF));
    xv[1] = bf2f((unsigned short)(u.x >> 16));
    xv[2] = bf2f((unsigned short)(u.y & 0xFFFF));
    xv[3] = bf2f((unsigned short)(u.y >> 16));
  } else {
    float4 v = *(const float4*)((const float*)x + (size_t)row * FIN_ + lane * 4);
    xv[0] = v.x; xv[1] = v.y; xv[2] = v.z; xv[3] = v.w;
  }
  float s = 0.f, d = 0.f;
#pragma unroll
  for (int i = 0; i < 4; i++) {
    s += xv[i] * wa_s[lane * 4 + i];
    d += xv[i] * wa_s[256 + lane * 4 + i];
  }
#pragma unroll
  for (int off = 32; off >= 1; off >>= 1) {
    s += __shfl_xor(s, off, 64);
    d += __shfl_xor(d, off, 64);
  }
  if (lane == 0) {
    fsrc[row] = s;
    fdst[row] = d;
  }
}

// ---------- kernel 2b: per-batch max of f_dst (8 blocks — cheap, proven) ----
__global__ void k_mdst(const float* __restrict__ fdst, float* __restrict__ Mdst) {
  int b = blockIdx.x;
  float mx = -1e30f;
  for (int i = threadIdx.x; i < N_; i += 256) mx = fmaxf(mx, fdst[b * N_ + i]);
  __shared__ float red[256];
  red[threadIdx.x] = mx;
  __syncthreads();
  for (int s = 128; s > 0; s >>= 1) {
    if (threadIdx.x < s) red[threadIdx.x] = fmaxf(red[threadIdx.x], red[threadIdx.x + s]);
    __syncthreads();
  }
  if (threadIdx.x == 0) Mdst[b] = red[0];
}

// ---------- kernel 3: gated attention; prefetched B-frags, single-bf16 p ----
// Grid = B*(N/16) = 1024 blocks, 256 threads. p -> LDS phi -> ds_read A-frag
// -> MFMA; B-fragments for tile t+1 register-prefetched before the barrier;
// denominator sums the same bf16(p) as the numerator (self-consistent).
__global__ __launch_bounds__(256)
void k_attn(const unsigned short* __restrict__ hT, const void* __restrict__ coord,
            const float* __restrict__ fsrc, const float* __restrict__ fdst,
            const float* __restrict__ Mdst, const int* __restrict__ flag,
            void* __restrict__ out) {
  const int isbf = *flag;
  const int tid = threadIdx.x;
  const int b   = blockIdx.x >> 7;
  const int q0  = (blockIdx.x & 127) * 16;

  __shared__ __align__(16) unsigned short phi[2][16][72];
  __shared__ __align__(16) float cjs[2][64][4];   // (cx,cy,cz,fdst)
  __shared__ float lred[16][16];                  // [jseg][qA]

  const int qA   = tid & 15;
  const int jseg = tid >> 4;
  const size_t qglb = (size_t)b * N_ + q0 + qA;
  const float cq0 = ldin(coord, qglb * 3 + 0, isbf);
  const float cq1 = ldin(coord, qglb * 3 + 1, isbf);
  const float cq2 = ldin(coord, qglb * 3 + 2, isbf);
  const float fsq = fsrc[qglb];
  const float Bq  = fmaxf(0.f, fsq + Mdst[b]);
  float lacc = 0.f;

  const int lane = tid & 63, w = tid >> 6;
  const int m = lane & 15, quad = lane >> 4;
  f32x4 acc[2];
  acc[0] = (f32x4){0.f, 0.f, 0.f, 0.f};
  acc[1] = (f32x4){0.f, 0.f, 0.f, 0.f};

  const unsigned short* hTb = hT + (size_t)b * (N_ * FOUT_);

  // prologue: coords tile 0 + B-fragments tile 0
  if (tid < 64) {
    size_t jg = (size_t)b * N_ + tid;
    cjs[0][tid][0] = ldin(coord, jg * 3 + 0, isbf);
    cjs[0][tid][1] = ldin(coord, jg * 3 + 1, isbf);
    cjs[0][tid][2] = ldin(coord, jg * 3 + 2, isbf);
    cjs[0][tid][3] = fdst[jg];
  }
  short8 bcur[4], bnxt[4];
#pragma unroll
  for (int ks = 0; ks < 2; ks++)
#pragma unroll
    for (int f2 = 0; f2 < 2; f2++) {
      int col = (w * 2 + f2) * 16 + m;
      bcur[ks * 2 + f2] = *(const short8*)&hTb[(size_t)(ks * 2 + (quad >> 1)) * (FOUT_ * 16)
                                               + col * 16 + (quad & 1) * 8];
    }
  __syncthreads();

  for (int t64 = 0; t64 < 32; t64++) {
    const int buf = t64 & 1, nbuf = buf ^ 1;

    // prefetch NEXT tile's B-fragments (global; consumed after next barrier)
    if (t64 < 31) {
      const int jcb = (t64 + 1) * 4;
#pragma unroll
      for (int ks = 0; ks < 2; ks++)
#pragma unroll
        for (int f2 = 0; f2 < 2; f2++) {
          int col = (w * 2 + f2) * 16 + m;
          bnxt[ks * 2 + f2] = *(const short8*)&hTb[(size_t)(jcb + ks * 2 + (quad >> 1)) * (FOUT_ * 16)
                                                   + col * 16 + (quad & 1) * 8];
        }
      // stage NEXT tile's coords
      if (tid < 64) {
        size_t jg = (size_t)b * N_ + (t64 + 1) * 64 + tid;
        cjs[nbuf][tid][0] = ldin(coord, jg * 3 + 0, isbf);
        cjs[nbuf][tid][1] = ldin(coord, jg * 3 + 1, isbf);
        cjs[nbuf][tid][2] = ldin(coord, jg * 3 + 2, isbf);
        cjs[nbuf][tid][3] = fdst[jg];
      }
    }

    // ---- logits -> bf16 p ----
#pragma unroll
    for (int jj = 0; jj < 4; jj++) {
      int jl = jseg * 4 + jj;
      float4 cj = *(const float4*)&cjs[buf][jl][0];
      float dx = cq0 - cj.x, dy = cq1 - cj.y, dz = cq2 - cj.z;
      float d2 = dx * dx + dy * dy + dz * dz;
      float loc = __expf(-0.1f * d2);
      float e = fsq + cj.w;
      e = (e > 0.f) ? e : 0.2f * e;
      float p = (loc > 0.01f) ? __expf(e * loc - Bq) : 0.f;
      unsigned short hb = f2bf(p);
      lacc += bf2f(hb);                 // denominator from the SAME bf16 values
      phi[buf][qA][jl] = hb;
    }
    __syncthreads();   // one barrier per tile

    // ---- PV MFMA with prefetched B ----
#pragma unroll
    for (int ks = 0; ks < 2; ks++) {
      short8 ah = *(const short8*)&phi[buf][m][ks * 32 + quad * 8];
#pragma unroll
      for (int f2 = 0; f2 < 2; f2++)
        acc[f2] = __builtin_amdgcn_mfma_f32_16x16x32_bf16(ah, bcur[ks * 2 + f2], acc[f2], 0, 0, 0);
    }
#pragma unroll
    for (int i = 0; i < 4; i++) bcur[i] = bnxt[i];
  }

  // ---- denominator ----
  lred[jseg][qA] = lacc;
  __syncthreads();
  float dinv[4];
#pragma unroll
  for (int r = 0; r < 4; r++) {
    int q = quad * 4 + r;
    float s = 0.f;
#pragma unroll
    for (int k = 0; k < 16; k++) s += lred[k][q];
    dinv[r] = 1.0f / fmaxf(s, 1e-30f);
  }

  // ---- normalize, elu, store ----
#pragma unroll
  for (int f2 = 0; f2 < 2; f2++) {
    int f = (w * 2 + f2) * 16 + m;
#pragma unroll
    for (int r = 0; r < 4; r++) {
      int q = quad * 4 + r;
      float v = acc[f2][r] * dinv[r];
      v = (v > 0.f) ? v : expm1f(v);
      size_t oidx = ((size_t)(b * N_ + q0 + q)) * FOUT_ + f;
      if (isbf) ((unsigned short*)out)[oidx] = f2bf(v);
      else      ((float*)out)[oidx] = v;
    }
  }
}

extern "C" void kernel_launch(void* const* d_in, const int* in_sizes, int n_in,
                              void* d_out, int out_size, void* d_ws, size_t ws_size,
                              hipStream_t stream) {
  const void* x     = d_in[0];
  const void* coord = d_in[1];
  const void* W     = d_in[2];
  const void* a     = d_in[3];

  // ws: [64-float header: flag @0][hT][WT][wa][fsrc][fdst][Mdst]
  int*            flag  = (int*)d_ws;
  unsigned short* hT    = (unsigned short*)((float*)d_ws + 64);
  unsigned short* WT    = hT + (size_t)NROWS * FOUT_;
  float*          wa    = (float*)(WT + 128 * 256);
  float*          fsrc  = wa + 512;
  float*          fdst  = fsrc + NROWS;
  float*          Mdst  = fdst + NROWS;

  k_detect<<<1, 256, 0, stream>>>(x, flag);
  k_prep  <<<129, 256, 0, stream>>>(W, a, flag, WT, wa);
  k_h     <<<NROWS / 32, 256, 0, stream>>>(x, WT, flag, hT);
  k_f     <<<NROWS / 4, 256, 0, stream>>>(x, wa, flag, fsrc, fdst);
  k_mdst  <<<B_, 256, 0, stream>>>(fdst, Mdst);
  k_attn  <<<B_ * (N_ / 16), 256, 0, stream>>>(hT, coord, fsrc, fdst, Mdst, flag, d_out);
}

// Round 10
// 143.681 us; speedup vs baseline: 2.4023x; 1.1279x over previous
//
#include <hip/hip_runtime.h>
#include <hip/hip_bf16.h>

#define B_    8
#define N_    2048
#define FIN_  256
#define FOUT_ 128
#define NROWS (B_*N_)

typedef __attribute__((ext_vector_type(8))) short short8;
typedef __attribute__((ext_vector_type(4))) float f32x4;

__device__ __forceinline__ float bf2f(unsigned short u) {
  return __uint_as_float(((unsigned int)u) << 16);
}
__device__ __forceinline__ unsigned short f2bf(float f) {
  unsigned int u = __float_as_uint(f);
  u += 0x7FFFu + ((u >> 16) & 1u);   // RNE
  return (unsigned short)(u >> 16);
}
__device__ __forceinline__ float ldin(const void* p, size_t idx, int isbf) {
  if (isbf) return bf2f(((const unsigned short*)p)[idx]);
  return ((const float*)p)[idx];
}

// ---------- kernel A: detect input dtype from x's bit patterns ----------
__global__ void k_detect(const void* x, int* flag) {
  __shared__ int cnt[256];
  const unsigned short* u = (const unsigned short*)x;
  int c = 0;
  for (int i = threadIdx.x; i < 8192; i += 256) {
    unsigned short v = u[i];
    int e = (v >> 7) & 0xFF;
    if ((e >= 110 && e <= 145) || (v & 0x7FFF) == 0) c++;
  }
  cnt[threadIdx.x] = c;
  __syncthreads();
  for (int s = 128; s > 0; s >>= 1) {
    if (threadIdx.x < s) cnt[threadIdx.x] += cnt[threadIdx.x + s];
    __syncthreads();
  }
  if (threadIdx.x == 0) *flag = (cnt[0] > 7373) ? 1 : 0;  // 0.9 * 8192
}

// ---------- kernel 0: blocks 0..127: WT[f][k] = bf16(W[k][f]);
//            block 128: wa[k] = W[k,:]@a_src, wa[256+k] = W[k,:]@a_dst (fp32)
__global__ __launch_bounds__(256)
void k_prep(const void* __restrict__ W, const void* __restrict__ a,
            const int* __restrict__ flag,
            unsigned short* __restrict__ WT, float* __restrict__ wa) {
  const int isbf = *flag;
  if (blockIdx.x < 128) {
    int f = blockIdx.x, k = threadIdx.x;
    WT[f * 256 + k] = f2bf(ldin(W, (size_t)k * 128 + f, isbf));
  } else {
    __shared__ float as_s[256];
    int k = threadIdx.x;
    as_s[k] = ldin(a, k, isbf);
    __syncthreads();
    float s = 0.f, d = 0.f;
    for (int f = 0; f < 128; f++) {
      float w = ldin(W, (size_t)k * 128 + f, isbf);
      s += w * as_s[f];
      d += w * as_s[128 + f];
    }
    wa[k] = s;
    wa[256 + k] = d;
  }
}

// ---------- kernel 1: h = x@W bf16 MFMA -> hT; FUSED fsrc/fdst = x@wa -------
// hT layout: (row j, feat f) at hT[(j>>4)*2048 + f*16 + (j&15)].
// The x@wa dots are computed from the ORIGINAL (fp32-exact) values during
// staging, so the logit path keeps fp32 accuracy.
__global__ __launch_bounds__(256)
void k_h(const void* __restrict__ x, const unsigned short* __restrict__ WT,
         const float* __restrict__ wa, const int* __restrict__ flag,
         unsigned short* __restrict__ hT, float* __restrict__ fsrc, float* __restrict__ fdst) {
  __shared__ __align__(16) unsigned short xs[32][264];
  __shared__ float wa_s[512];
  const int isbf = *flag;
  const int t    = threadIdx.x;
  const int row0 = blockIdx.x * 32;

  wa_s[t] = wa[t];
  wa_s[256 + t] = wa[256 + t];
  __syncthreads();          // wa_s visible before cross-thread dot reads

  const int c = t & 31;     // column segment (8 floats)
  float sp[4], dp[4];
  if (isbf) {
    const unsigned short* xu = (const unsigned short*)x;
#pragma unroll
    for (int u = 0; u < 4; u++) {
      int r = u * 8 + (t >> 5);
      short8 sh = *(const short8*)&xu[(size_t)(row0 + r) * FIN_ + c * 8];
      *(short8*)&xs[r][c * 8] = sh;
      float s = 0.f, d = 0.f;
#pragma unroll
      for (int e = 0; e < 8; e++) {
        float xv = bf2f((unsigned short)sh[e]);
        s += xv * wa_s[c * 8 + e];
        d += xv * wa_s[256 + c * 8 + e];
      }
      sp[u] = s; dp[u] = d;
    }
  } else {
    const float* xf = (const float*)x;
#pragma unroll
    for (int u = 0; u < 4; u++) {
      int r = u * 8 + (t >> 5);
      float4 v0 = *(const float4*)&xf[(size_t)(row0 + r) * FIN_ + c * 8];
      float4 v1 = *(const float4*)&xf[(size_t)(row0 + r) * FIN_ + c * 8 + 4];
      float vv[8] = {v0.x, v0.y, v0.z, v0.w, v1.x, v1.y, v1.z, v1.w};
      short8 sh;
      float s = 0.f, d = 0.f;
#pragma unroll
      for (int e = 0; e < 8; e++) {
        sh[e] = (short)f2bf(vv[e]);
        s += vv[e] * wa_s[c * 8 + e];
        d += vv[e] * wa_s[256 + c * 8 + e];
      }
      *(short8*)&xs[r][c * 8] = sh;
      sp[u] = s; dp[u] = d;
    }
  }
  // half-wave (32-lane) reduce over the column dimension
#pragma unroll
  for (int off = 16; off >= 1; off >>= 1) {
#pragma unroll
    for (int u = 0; u < 4; u++) {
      sp[u] += __shfl_xor(sp[u], off, 64);
      dp[u] += __shfl_xor(dp[u], off, 64);
    }
  }
  if (c == 0) {
#pragma unroll
    for (int u = 0; u < 4; u++) {
      int r = u * 8 + (t >> 5);
      fsrc[row0 + r] = sp[u];
      fdst[row0 + r] = dp[u];
    }
  }
  __syncthreads();

  const int lane = t & 63, w = t >> 6;
  const int m = lane & 15, quad = lane >> 4;
  const int slab = w >> 1, fh = w & 1;

  f32x4 acc[4];
#pragma unroll
  for (int i = 0; i < 4; i++) acc[i] = (f32x4){0.f, 0.f, 0.f, 0.f};

#pragma unroll
  for (int ks = 0; ks < 8; ks++) {
    short8 ah = *(const short8*)&xs[slab * 16 + m][ks * 32 + quad * 8];
#pragma unroll
    for (int ft = 0; ft < 4; ft++) {
      int f = fh * 64 + ft * 16 + m;
      short8 bh = *(const short8*)&WT[(size_t)f * 256 + ks * 32 + quad * 8];
      acc[ft] = __builtin_amdgcn_mfma_f32_16x16x32_bf16(ah, bh, acc[ft], 0, 0, 0);
    }
  }

  size_t n0 = (size_t)blockIdx.x * 2 + slab;
  unsigned short* hblk = hT + n0 * (FOUT_ * 16);
#pragma unroll
  for (int ft = 0; ft < 4; ft++) {
    int f = fh * 64 + ft * 16 + m;
    unsigned short p0 = f2bf(acc[ft][0]), p1 = f2bf(acc[ft][1]);
    unsigned short p2 = f2bf(acc[ft][2]), p3 = f2bf(acc[ft][3]);
    *(uint2*)&hblk[f * 16 + quad * 4] = make_uint2(
        (unsigned)p0 | ((unsigned)p1 << 16),
        (unsigned)p2 | ((unsigned)p3 << 16));
  }
}

// ---------- kernel 2: per-batch max of f_dst ----------
__global__ void k_mdst(const float* __restrict__ fdst, float* __restrict__ Mdst) {
  int b = blockIdx.x;
  float mx = -1e30f;
  for (int i = threadIdx.x; i < N_; i += 256) mx = fmaxf(mx, fdst[b * N_ + i]);
  __shared__ float red[256];
  red[threadIdx.x] = mx;
  __syncthreads();
  for (int s = 128; s > 0; s >>= 1) {
    if (threadIdx.x < s) red[threadIdx.x] = fmaxf(red[threadIdx.x], red[threadIdx.x + s]);
    __syncthreads();
  }
  if (threadIdx.x == 0) Mdst[b] = red[0];
}

// ---------- kernel 3: gated attention, 128-j tiles, half-staged static cjs --
// Grid = B*(N/16) = 1024 blocks, 256 threads. Verified round-9 dataflow
// (p -> LDS phi -> ds_read A-frag -> MFMA, B-frags register-prefetched), plus:
//  * 1024-row coord/fdst LDS cache, restaged once at midpoint -> ~19 barriers
//  * 8 pairs/thread/iter (2x exp-chain ILP), packed uint4 phi store
__global__ __launch_bounds__(256, 4)
void k_attn(const unsigned short* __restrict__ hT, const void* __restrict__ coord,
            const float* __restrict__ fsrc, const float* __restrict__ fdst,
            const float* __restrict__ Mdst, const int* __restrict__ flag,
            void* __restrict__ out) {
  const int isbf = *flag;
  const int tid = threadIdx.x;
  const int b   = blockIdx.x >> 7;
  const int q0  = (blockIdx.x & 127) * 16;

  __shared__ __align__(16) float4 cjs[1024];            // 16 KB (cx,cy,cz,fdst)
  __shared__ __align__(16) unsigned short phi[2][16][136];
  __shared__ float lred[16][16];                        // [jseg][qA]

  const int qA   = tid & 15;
  const int jseg = tid >> 4;                            // 0..15, 8 j's each
  const size_t qglb = (size_t)b * N_ + q0 + qA;
  const float cq0 = ldin(coord, qglb * 3 + 0, isbf);
  const float cq1 = ldin(coord, qglb * 3 + 1, isbf);
  const float cq2 = ldin(coord, qglb * 3 + 2, isbf);
  const float fsq = fsrc[qglb];
  const float Bq  = fmaxf(0.f, fsq + Mdst[b]);
  float lacc = 0.f;

  const int lane = tid & 63, w = tid >> 6;
  const int m = lane & 15, quad = lane >> 4;
  f32x4 acc[2];
  acc[0] = (f32x4){0.f, 0.f, 0.f, 0.f};
  acc[1] = (f32x4){0.f, 0.f, 0.f, 0.f};

  const unsigned short* hTb = hT + (size_t)b * (N_ * FOUT_);
  const int colA = (w * 2 + 0) * 16 + m;
  const int colB = (w * 2 + 1) * 16 + m;
  const int co   = (quad & 1) * 8;
  const int chq  = quad >> 1;

  // stage half 0 (j in [0,1024))
  for (int r = tid; r < 1024; r += 256) {
    size_t jg = (size_t)b * N_ + r;
    cjs[r] = make_float4(ldin(coord, jg * 3 + 0, isbf), ldin(coord, jg * 3 + 1, isbf),
                         ldin(coord, jg * 3 + 2, isbf), fdst[jg]);
  }
  // prefetch B-fragments, tile 0
  short8 bcur[8], bnxt[8];
#pragma unroll
  for (int ks = 0; ks < 4; ks++) {
    size_t base = (size_t)(ks * 2 + chq) * (FOUT_ * 16) + co;
    bcur[ks * 2 + 0] = *(const short8*)&hTb[base + colA * 16];
    bcur[ks * 2 + 1] = *(const short8*)&hTb[base + colB * 16];
  }
  __syncthreads();

  for (int t = 0; t < 16; t++) {
    if (t == 8) {
      // all waves are past barrier_7 (done reading half 0); restage half 1
      for (int r = tid; r < 1024; r += 256) {
        size_t jg = (size_t)b * N_ + 1024 + r;
        cjs[r] = make_float4(ldin(coord, jg * 3 + 0, isbf), ldin(coord, jg * 3 + 1, isbf),
                             ldin(coord, jg * 3 + 2, isbf), fdst[jg]);
      }
      __syncthreads();
    }
    const int buf = t & 1;

    // prefetch NEXT tile's B-fragments (consumed after next barrier)
    if (t < 15) {
      const int jcb = (t + 1) * 8;
#pragma unroll
      for (int ks = 0; ks < 4; ks++) {
        size_t base = (size_t)(jcb + ks * 2 + chq) * (FOUT_ * 16) + co;
        bnxt[ks * 2 + 0] = *(const short8*)&hTb[base + colA * 16];
        bnxt[ks * 2 + 1] = *(const short8*)&hTb[base + colB * 16];
      }
    }

    // ---- logits: 8 pairs -> packed bf16 -> one uint4 LDS store ----
    const int jbase = (t & 7) * 128 + jseg * 8;
    unsigned pk[4];
#pragma unroll
    for (int jp = 0; jp < 4; jp++) {
      unsigned short hb[2];
#pragma unroll
      for (int h = 0; h < 2; h++) {
        float4 cj = cjs[jbase + jp * 2 + h];
        float dx = cq0 - cj.x, dy = cq1 - cj.y, dz = cq2 - cj.z;
        float d2 = dx * dx + dy * dy + dz * dz;
        float loc = __expf(-0.1f * d2);
        float e = fsq + cj.w;
        e = fmaxf(e, 0.2f * e);                     // leaky relu, branch-free
        float p = (loc > 0.01f) ? __expf(e * loc - Bq) : 0.f;
        hb[h] = f2bf(p);
        lacc += bf2f(hb[h]);        // denominator from the SAME bf16 values
      }
      pk[jp] = (unsigned)hb[0] | ((unsigned)hb[1] << 16);
    }
    *(uint4*)&phi[buf][qA][jseg * 8] = make_uint4(pk[0], pk[1], pk[2], pk[3]);
    __syncthreads();   // one barrier per 128-j tile

    // ---- PV MFMA: 4 k-steps of 32, 2 f-tiles ----
#pragma unroll
    for (int ks = 0; ks < 4; ks++) {
      short8 ah = *(const short8*)&phi[buf][m][ks * 32 + quad * 8];
      acc[0] = __builtin_amdgcn_mfma_f32_16x16x32_bf16(ah, bcur[ks * 2 + 0], acc[0], 0, 0, 0);
      acc[1] = __builtin_amdgcn_mfma_f32_16x16x32_bf16(ah, bcur[ks * 2 + 1], acc[1], 0, 0, 0);
    }
#pragma unroll
    for (int i = 0; i < 8; i++) bcur[i] = bnxt[i];
  }

  // ---- denominator ----
  lred[jseg][qA] = lacc;
  __syncthreads();
  float dinv[4];
#pragma unroll
  for (int r = 0; r < 4; r++) {
    int q = quad * 4 + r;
    float s = 0.f;
#pragma unroll
    for (int k = 0; k < 16; k++) s += lred[k][q];
    dinv[r] = 1.0f / fmaxf(s, 1e-30f);
  }

  // ---- normalize, elu, store (D: row q = quad*4+r, col f) ----
#pragma unroll
  for (int f2 = 0; f2 < 2; f2++) {
    int f = (w * 2 + f2) * 16 + m;
#pragma unroll
    for (int r = 0; r < 4; r++) {
      int q = quad * 4 + r;
      float v = acc[f2][r] * dinv[r];
      v = (v > 0.f) ? v : expm1f(v);
      size_t oidx = ((size_t)(b * N_ + q0 + q)) * FOUT_ + f;
      if (isbf) ((unsigned short*)out)[oidx] = f2bf(v);
      else      ((float*)out)[oidx] = v;
    }
  }
}

extern "C" void kernel_launch(void* const* d_in, const int* in_sizes, int n_in,
                              void* d_out, int out_size, void* d_ws, size_t ws_size,
                              hipStream_t stream) {
  const void* x     = d_in[0];
  const void* coord = d_in[1];
  const void* W     = d_in[2];
  const void* a     = d_in[3];

  // ws: [64-float header: flag @0][hT][WT][wa][fsrc][fdst][Mdst]
  int*            flag  = (int*)d_ws;
  unsigned short* hT    = (unsigned short*)((float*)d_ws + 64);
  unsigned short* WT    = hT + (size_t)NROWS * FOUT_;
  float*          wa    = (float*)(WT + 128 * 256);
  float*          fsrc  = wa + 512;
  float*          fdst  = fsrc + NROWS;
  float*          Mdst  = fdst + NROWS;

  k_detect<<<1, 256, 0, stream>>>(x, flag);
  k_prep  <<<129, 256, 0, stream>>>(W, a, flag, WT, wa);
  k_h     <<<NROWS / 32, 256, 0, stream>>>(x, WT, wa, flag, hT, fsrc, fdst);
  k_mdst  <<<B_, 256, 0, stream>>>(fdst, Mdst);
  k_attn  <<<B_ * (N_ / 16), 256, 0, stream>>>(hT, coord, fsrc, fdst, Mdst, flag, d_out);
}